// Round 15
// baseline (113.752 us; speedup 1.0000x reference)
//
#include <hip/hip_runtime.h>
#include <hip/hip_bf16.h>

typedef __attribute__((ext_vector_type(8))) short short8;
typedef __attribute__((ext_vector_type(4))) float floatx4;

#define IMGH 112
#define IMGW 112
#define SHIFT 3
#define NWIN 49

#define XSTR 152     // s_xp row stride (x / P / O)
#define QKSTR 280    // s_qk row stride (Q 0-127, K 128-255)
#define VTSTR 88     // s_vt row stride (V^T)

#define LOG2E 1.4426950408889634f
#define QSCALE (0.17677669529663687f * LOG2E)
#define NMASK (-100.0f * LOG2E)

__device__ inline unsigned short f2bf1(float f) {
    unsigned r;
    asm("v_cvt_pk_bf16_f32 %0, %1, %1" : "=v"(r) : "v"(f));
    return (unsigned short)r;
}
__device__ inline unsigned cvtpk(float lo, float hi) {
    unsigned r;
    asm("v_cvt_pk_bf16_f32 %0, %1, %2" : "=v"(r) : "v"(lo), "v"(hi));
    return r;
}

__device__ inline floatx4 mfma16(short8 a, short8 b, floatx4 c) {
    return __builtin_amdgcn_mfma_f32_16x16x32_bf16(a, b, c, 0, 0, 0);
}
__device__ inline floatx4 zero4() {
    floatx4 z; z[0] = 0.f; z[1] = 0.f; z[2] = 0.f; z[3] = 0.f; return z;
}
__device__ inline short8 ones8() {          // bf16 1.0 in all 8 slots
    short8 z;
    #pragma unroll
    for (int i = 0; i < 8; ++i) z[i] = (short)0x3F80;
    return z;
}

// weight fp32 -> bf16 (Q rows pre-scaled by scale*log2e)
__global__ __launch_bounds__(256) void convert_w(const float* __restrict__ qkv_w,
                                                 const float* __restrict__ proj_w,
                                                 short* __restrict__ ws) {
    int i = blockIdx.x * 256 + threadIdx.x;
    if (i < 49152) {
        float v = qkv_w[i];
        if (i < 16384) v *= QSCALE;          // rows 0..127 = Q features
        ws[i] = (short)f2bf1(v);
    }
    if (i < 16384) ws[49152 + i] = (short)f2bf1(proj_w[i]);
}

// One block per 7x7 window, 8 waves. Operand-swapped MFMAs so every epilogue
// store is c-contiguous -> packed b64/dwordx4 writes; MFMA row-sum softmax.
__global__ __launch_bounds__(512, 4) void win_attn_mfma8(
    const float* __restrict__ x,
    const float* __restrict__ qkv_b,
    const float* __restrict__ proj_b,
    const float* __restrict__ rpb,
    const short* __restrict__ wq,    // bf16 qkv_w [384][128] (Q rows scaled)
    const short* __restrict__ wp,    // bf16 proj_w [128][128]
    float* __restrict__ out)
{
    __shared__ alignas(16) short s_xp[64 * XSTR];    // x -> P slots -> O
    __shared__ alignas(16) short s_qk[64 * QKSTR];
    __shared__ alignas(16) short s_vt[128 * VTSTR];
    __shared__ float2 s_rpb[2][169];                 // pre-scaled by LOG2E
    __shared__ int s_meta[64];                       // t13 | reg<<8
    __shared__ int s_gout[64];                       // scatter pixel index

    const int tid = threadIdx.x;
    const int w    = tid >> 6;         // wave 0..7
    const int l    = tid & 63;
    const int l15  = l & 15;
    const int lg   = l >> 4;           // 0..3
    const int hgrp = w >> 2;           // head pair 0/1
    const int m_w  = w & 3;            // query row tile

    const int blk = blockIdx.x;
    const int b   = blk >> 8;
    const int wi  = blk & 255;
    const int hs0 = (wi >> 4) * 7;
    const int ws0 = (wi & 15) * 7;

    const float* xb = x + (size_t)b * (IMGH * IMGW * 128);

    // ---- stage 0: metadata + rpb + x -> LDS ----
    if (tid < 64) {
        int rowc = tid < NWIN ? tid : NWIN - 1;
        int ri = (rowc * 9363) >> 16;
        int ci = rowc - ri * 7;
        int hc = hs0 + ri, wc = ws0 + ci;
        int reg = (hc < 105 ? 0 : (hc < 109 ? 1 : 2)) * 3
                + (wc < 105 ? 0 : (wc < 109 ? 1 : 2));
        if (tid >= NWIN) reg = 255;
        s_meta[tid] = (ri * 13 + ci) | (reg << 8);
        int gh = hc + SHIFT; if (gh >= IMGH) gh -= IMGH;
        int gw = wc + SHIFT; if (gw >= IMGW) gw -= IMGW;
        s_gout[tid] = gh * IMGW + gw;
    }
    if (tid < 338) {
        int hg  = tid < 169 ? 0 : 1;
        int idx = tid - hg * 169;
        float2 v = *(const float2*)(rpb + idx * 4 + hg * 2);
        v.x *= LOG2E; v.y *= LOG2E;
        s_rpb[hg][idx] = v;
    }
    {
        int row  = tid >> 3;           // 0..63
        int col0 = (tid & 7) << 4;     // 0,16,...,112
        uint4 u0 = {0,0,0,0}, u1 = {0,0,0,0};
        if (row < NWIN) {
            int rr = (row * 9363) >> 16;
            int cc = row - rr * 7;
            int gh = hs0 + rr + SHIFT; if (gh >= IMGH) gh -= IMGH;
            int gw = ws0 + cc + SHIFT; if (gw >= IMGW) gw -= IMGW;
            const float* px = xb + (((size_t)(gh * IMGW + gw)) << 7) + col0;
            float4 a = *(const float4*)(px + 0);
            float4 c4 = *(const float4*)(px + 4);
            float4 e = *(const float4*)(px + 8);
            float4 g = *(const float4*)(px + 12);
            u0.x = cvtpk(a.x, a.y);   u0.y = cvtpk(a.z, a.w);
            u0.z = cvtpk(c4.x, c4.y); u0.w = cvtpk(c4.z, c4.w);
            u1.x = cvtpk(e.x, e.y);   u1.y = cvtpk(e.z, e.w);
            u1.z = cvtpk(g.x, g.y);   u1.w = cvtpk(g.z, g.w);
        }
        *(uint4*)&s_xp[row * XSTR + col0]     = u0;
        *(uint4*)&s_xp[row * XSTR + col0 + 8] = u1;
    }
    __syncthreads();

    // ---- stage 1: qkv GEMM. wave w owns n-tiles [3w, 3w+3) of 24 ----
    {
        short8 bfr[3][4];
        float4 biasq[3];           // per-feature bias (Q/K tiles)
        float  biasv[3];           // per-feature bias (V tiles, feature = l15)
        #pragma unroll
        for (int i = 0; i < 3; ++i) {
            int j0 = (w * 3 + i) << 4;
            const short* wb = wq + ((j0 + l15) << 7) + lg * 8;
            #pragma unroll
            for (int kk = 0; kk < 4; ++kk) bfr[i][kk] = *(const short8*)(wb + kk * 32);
            float4 b4 = *(const float4*)(qkv_b + j0 + lg * 4);
            if (j0 < 128) { b4.x *= QSCALE; b4.y *= QSCALE; b4.z *= QSCALE; b4.w *= QSCALE; }
            biasq[i] = b4;
            biasv[i] = qkv_b[j0 + l15];
        }
        for (int m = 0; m < 4; ++m) {
            short8 af[4];
            #pragma unroll
            for (int kk = 0; kk < 4; ++kk)
                af[kk] = *(const short8*)&s_xp[(m * 16 + l15) * XSTR + kk * 32 + lg * 8];
            #pragma unroll
            for (int i = 0; i < 3; ++i) {
                int j0 = (w * 3 + i) << 4;
                if (j0 < 256) {
                    // swapped: D[feature][token] -> packed row-major Q/K store
                    floatx4 acc = zero4();
                    #pragma unroll
                    for (int kk = 0; kk < 4; ++kk) acc = mfma16(bfr[i][kk], af[kk], acc);
                    uint2 u;
                    u.x = cvtpk(acc[0] + biasq[i].x, acc[1] + biasq[i].y);
                    u.y = cvtpk(acc[2] + biasq[i].z, acc[3] + biasq[i].w);
                    *(uint2*)&s_qk[(m * 16 + l15) * QKSTR + j0 + lg * 4] = u;
                } else {
                    // original: D[token][feature] -> packed V^T store
                    floatx4 acc = zero4();
                    #pragma unroll
                    for (int kk = 0; kk < 4; ++kk) acc = mfma16(af[kk], bfr[i][kk], acc);
                    uint2 u;
                    u.x = cvtpk(acc[0] + biasv[i], acc[1] + biasv[i]);
                    u.y = cvtpk(acc[2] + biasv[i], acc[3] + biasv[i]);
                    *(uint2*)&s_vt[(j0 - 256 + l15) * VTSTR + m * 16 + lg * 4] = u;
                }
            }
        }
    }
    __syncthreads();   // x consumed; s_xp becomes P/O storage

    // ---- bias+mask tables: query = l15 (fixed), key = n*16+lg*4+c ----
    float b2x[4][4], b2y[4][4];   // [n][c]
    {
        int mi = s_meta[m_w * 16 + l15];
        int ti = mi & 255, gi = mi >> 8;
        #pragma unroll
        for (int n = 0; n < 4; ++n) {
            int4 mk = *(const int4*)&s_meta[n * 16 + lg * 4];
            #pragma unroll
            for (int c = 0; c < 4; ++c) {
                int mv = (&mk.x)[c];
                int d = ti - (mv & 255) + 84;
                float msk = (gi == (mv >> 8)) ? 0.f : NMASK;
                float2 r2 = s_rpb[hgrp][d];
                b2x[n][c] = r2.x + msk;
                b2y[n][c] = r2.y + msk;
            }
        }
    }

    // ---- stage 2: swapped QK^T (D[key][query]) + packed P + swapped PV ----
    floatx4 accO[2][2];    // [hh][vt], D[feat][query]
    float   inv2[2];
    const short8 vone = ones8();
    #pragma unroll
    for (int hh = 0; hh < 2; ++hh) {
        const int h = hgrp * 2 + hh;
        short8 qf = *(const short8*)&s_qk[(m_w * 16 + l15) * QKSTR + h * 32 + lg * 8];
        floatx4 accS[4];
        #pragma unroll
        for (int n = 0; n < 4; ++n) {
            short8 kf = *(const short8*)&s_qk[(n * 16 + l15) * QKSTR + 128 + h * 32 + lg * 8];
            accS[n] = mfma16(kf, qf, zero4());   // D[key][query]
        }
        // no-max exp2 (bounded logits; masked/pad keys -> -144 -> 0)
        #pragma unroll
        for (int n = 0; n < 4; ++n) {
            float p0 = exp2f(accS[n][0] + (hh ? b2y[n][0] : b2x[n][0]));
            float p1 = exp2f(accS[n][1] + (hh ? b2y[n][1] : b2x[n][1]));
            float p2 = exp2f(accS[n][2] + (hh ? b2y[n][2] : b2x[n][2]));
            float p3 = exp2f(accS[n][3] + (hh ? b2y[n][3] : b2x[n][3]));
            uint2 u;
            u.x = cvtpk(p0, p1);
            u.y = cvtpk(p2, p3);
            *(uint2*)&s_xp[(m_w * 16 + l15) * XSTR + hgrp * 72 + n * 16 + lg * 4] = u;
        }
        short8 pa[2];
        #pragma unroll
        for (int kt = 0; kt < 2; ++kt)
            pa[kt] = *(const short8*)&s_xp[(m_w * 16 + l15) * XSTR + hgrp * 72 + kt * 32 + lg * 8];
        floatx4 accSum = zero4();
        #pragma unroll
        for (int vt = 0; vt < 2; ++vt) accO[hh][vt] = zero4();
        #pragma unroll
        for (int kt = 0; kt < 2; ++kt) {
            #pragma unroll
            for (int vt = 0; vt < 2; ++vt) {
                short8 vf = *(const short8*)&s_vt[(h * 32 + vt * 16 + l15) * VTSTR + kt * 32 + lg * 8];
                accO[hh][vt] = mfma16(vf, pa[kt], accO[hh][vt]);   // D[feat][query]
            }
            accSum = mfma16(vone, pa[kt], accSum);                 // D[*][query=l15]
        }
        inv2[hh] = 1.f / accSum[0];
    }
    __syncthreads();   // all P consumed before O overwrites s_xp

    // ---- O (normalized, packed) -> s_xp[query=l15 row][feat] ----
    #pragma unroll
    for (int hh = 0; hh < 2; ++hh)
        #pragma unroll
        for (int vt = 0; vt < 2; ++vt) {
            uint2 u;
            u.x = cvtpk(accO[hh][vt][0] * inv2[hh], accO[hh][vt][1] * inv2[hh]);
            u.y = cvtpk(accO[hh][vt][2] * inv2[hh], accO[hh][vt][3] * inv2[hh]);
            *(uint2*)&s_xp[(m_w * 16 + l15) * XSTR + hgrp * 64 + hh * 32 + vt * 16 + lg * 4] = u;
        }
    __syncthreads();

    // ---- stage 3: swapped proj (D[outfeat][token]) + dwordx4 scatter ----
    {
        floatx4 acc[4];
        #pragma unroll
        for (int m = 0; m < 4; ++m) acc[m] = zero4();
        const short* wbp = wp + ((w * 16 + l15) << 7) + lg * 8;
        #pragma unroll
        for (int kk = 0; kk < 4; ++kk) {
            short8 pw = *(const short8*)(wbp + kk * 32);
            #pragma unroll
            for (int m = 0; m < 4; ++m) {
                short8 of = *(const short8*)&s_xp[(m * 16 + l15) * XSTR + kk * 32 + lg * 8];
                acc[m] = mfma16(pw, of, acc[m]);
            }
        }
        float4 pb = *(const float4*)(proj_b + w * 16 + lg * 4);
        const size_t obase = (size_t)b * (IMGH * IMGW);
        #pragma unroll
        for (int m = 0; m < 4; ++m) {
            int token = m * 16 + l15;
            if (token < NWIN) {
                float4 o4;
                o4.x = acc[m][0] + pb.x;
                o4.y = acc[m][1] + pb.y;
                o4.z = acc[m][2] + pb.z;
                o4.w = acc[m][3] + pb.w;
                *(float4*)&out[((obase + s_gout[token]) << 7) + w * 16 + lg * 4] = o4;
            }
        }
    }
}

extern "C" void kernel_launch(void* const* d_in, const int* in_sizes, int n_in,
                              void* d_out, int out_size, void* d_ws, size_t ws_size,
                              hipStream_t stream) {
    const float* x      = (const float*)d_in[0];
    const float* qkv_w  = (const float*)d_in[1];
    const float* qkv_b  = (const float*)d_in[2];
    const float* proj_w = (const float*)d_in[3];
    const float* proj_b = (const float*)d_in[4];
    const float* rpb    = (const float*)d_in[5];
    float* out = (float*)d_out;
    short* wbf = (short*)d_ws;   // [0,49152) qkv_w bf16 (Q rows pre-scaled), [49152,65536) proj_w

    hipLaunchKernelGGL(convert_w, dim3(192), dim3(256), 0, stream, qkv_w, proj_w, wbf);
    hipLaunchKernelGGL(win_attn_mfma8, dim3(4096), dim3(512), 0, stream,
                       x, qkv_b, proj_b, rpb, wbf, wbf + 49152, out);
}